// Round 6
// baseline (1352.700 us; speedup 1.0000x reference)
//
#include <hip/hip_runtime.h>

#define N_ROWS 65536
#define K_CODES 8192
#define DIM 256
#define CAP 56

// d_out layout (floats): [quantized_st 65536*256][loss 1][indices 65536]
#define LOSS_OFF (N_ROWS * DIM)
#define IDX_OFF (LOSS_OFF + 1)
// scratch inside d_out's quantized region (consumed before gather overwrites):
#define OUT_WBF_U16 0              // W_bf: 8192*256 u16  (4 MB)
#define OUT_ZBF_U16 2097152        // z_bf: 65536*256 u16 (32 MB)
#define OUT_CAND_F 9437184         // cand: 65536*56 uint2 (29.36 MB); ends exactly at 16777216

// d_ws layout (4-byte units), ~1.85 MB total
#define WS_LOSS 0
#define WS_ZNORM 64
#define WS_WNORM (WS_ZNORM + N_ROWS)
#define WS_MARGIN (WS_WNORM + K_CODES)
#define WS_CUT0 (WS_MARGIN + N_ROWS)
#define WS_CNT (WS_CUT0 + N_ROWS)       // uint
#define WS_OVF (WS_CNT + N_ROWS)        // uint counter
#define WS_OVFLIST (WS_OVF + 1)         // uint, up to N_ROWS
#define WS_SLOT (((WS_OVFLIST + N_ROWS) + 1) & ~1)  // u64 per row (8B aligned), 2*N_ROWS u32

typedef __bf16 bf16x8 __attribute__((ext_vector_type(8)));
typedef float f32x4 __attribute__((ext_vector_type(4)));

// ---------- numerics helpers ----------

__device__ __forceinline__ float mul_rn_nofma(float a, float b) {
  float r;
  asm("v_mul_f32 %0, %1, %2" : "=v"(r) : "v"(a), "v"(b));
  return r;
}

// fp32 -> bf16 bits, RNE (error <= 2^-8 rel; the margin derivation assumes this).
__device__ __forceinline__ unsigned int f2bf(float f) {
  unsigned int u = __float_as_uint(f);
  return (u + 0x7FFFu + ((u >> 16) & 1u)) >> 16;
}

// Exact np matmul replica: single ascending-d fmaf chain (bit-proven rounds 1-5).
__device__ float dot_chain(const float* __restrict__ zp, const float* __restrict__ wp) {
  float acc = 0.0f;
#pragma unroll 8
  for (int d4 = 0; d4 < 64; ++d4) {
    const float4 a = *(const float4*)(zp + d4 * 4);
    const float4 b = *(const float4*)(wp + d4 * 4);
    acc = fmaf(a.x, b.x, acc);
    acc = fmaf(a.y, b.y, acc);
    acc = fmaf(a.z, b.z, acc);
    acc = fmaf(a.w, b.w, acc);
  }
  return acc;
}

// global -> LDS 16B DMA (wave-uniform LDS base + lane*16).
__device__ __forceinline__ void glds16(const void* g, void* l) {
  __builtin_amdgcn_global_load_lds(
      (const __attribute__((address_space(1))) void*)(unsigned long long)(size_t)g,
      (__attribute__((address_space(3))) void*)(unsigned int)(size_t)l, 16, 0, 0);
}

// ---------- kernels ----------

// FUSED precvt+norms: one pass over z and W computes the exact numpy-pairwise
// norms (reduction structure UNCHANGED - bit-exact dist replication depends on
// it), the screen cut, AND emits the bf16 copies.
__global__ void prep_kernel(const float* __restrict__ z, const float* __restrict__ W,
                            float* __restrict__ ws, unsigned short* __restrict__ outu) {
  const int tid = threadIdx.x;
  const int l = tid & 63, w = tid >> 6;
  const int j = l & 7, b = (l >> 3) & 1, rw = l >> 4;
  const int row = blockIdx.x * 16 + w * 4 + rw;  // 0 .. 73727
  const bool isz = (row < N_ROWS);
  const float* src = isz ? (z + (size_t)row * DIM + b * 128)
                         : (W + (size_t)(row - N_ROWS) * DIM + b * 128);
  unsigned short* dst = isz ? (outu + OUT_ZBF_U16 + (size_t)row * DIM + b * 128)
                            : (outu + OUT_WBF_U16 + (size_t)(row - N_ROWS) * DIM + b * 128);
  float a0 = src[j];
  dst[j] = (unsigned short)f2bf(a0);
  float r = mul_rn_nofma(a0, a0);
  float s = fabsf(a0);
  for (int i = 8; i < 128; i += 8) {
    const float v = src[i + j];
    dst[i + j] = (unsigned short)f2bf(v);
    r = r + mul_rn_nofma(v, v);
    s = s + fabsf(v);
  }
  // exact numpy pairwise tree: ((r0+r1)+(r2+r3))+((r4+r5)+(r6+r7)), then blk0+blk1
  r = r + __shfl_xor(r, 1, 64);
  r = r + __shfl_xor(r, 2, 64);
  r = r + __shfl_xor(r, 4, 64);
  r = r + __shfl_xor(r, 8, 64);
  s = s + __shfl_xor(s, 1, 64);
  s = s + __shfl_xor(s, 2, 64);
  s = s + __shfl_xor(s, 4, 64);
  s = s + __shfl_xor(s, 8, 64);
  if ((l & 15) == 0) {
    if (isz) {
      ws[WS_ZNORM + row] = r;
      const float margin = 2.0e-6f * s + 4.0e-5f;
      ws[WS_MARGIN + row] = margin;
      ws[WS_CUT0 + row] = 3.10f * sqrtf(r) * 7.0467e-5f - margin;
      ((unsigned int*)ws)[WS_CNT + row] = 0u;
    } else {
      ws[WS_WNORM + (row - N_ROWS)] = r;
    }
  }
  if (blockIdx.x == 0 && tid == 0) {
    ws[WS_LOSS] = 0.0f;
    ((unsigned int*)ws)[WS_OVF] = 0u;
  }
}

// bf16 MFMA screen GEMM - r4 step (proven bit-exact, 0 conflicts) CHAINED over
// 8 row-tiles per block. Theory (r5 post-mortem): r0/r4's 24% MFMA packing vs
// m97's 44% (identical per-step structure) is fill/drain (2 of 4 steps) +
// 32768-block churn. Chain = 64-step K-pipeline per block (fill/drain 2/64),
// 4096 blocks (8x less churn), counted-vmcnt prefetch carried ACROSS tile
// boundaries, register-only per-tile epilogue overlapped with in-flight DMA.
// MFMA K-slice order per output tile unchanged (ascending 32-wide slices,
// same fragment map) -> acc bits identical -> candidate set & proof intact.
__global__ __launch_bounds__(256) void gemm_screen_kernel(
    const unsigned short* __restrict__ zbf, const unsigned short* __restrict__ wbf,
    float* __restrict__ ws, uint2* __restrict__ candp) {
  __shared__ __align__(16) unsigned short As[2][128][32];
  __shared__ __align__(16) unsigned short Bs[2][128][32];

  const int tid = threadIdx.x;
  const int w = tid >> 6, l = tid & 63;
  const int lr = l & 15, lq = l >> 4;
  const int wr = (w >> 1) * 64, wc = (w & 1) * 64;
  const int colBase = blockIdx.x * 128;   // fixed W cols for this block
  const int gBase = blockIdx.y * 1024;    // 8 row-tiles of 128

  unsigned int* cntp = (unsigned int*)ws + WS_CNT;

  // glds16 dest is linear: lane l -> row base+(l>>2), chunk l&3 (64-B rows).
  // Source pre-swizzled: ga = (l&3) ^ ((row>>1)&3) = (l&3) ^ ((l>>3)&3).
  const int ga0 = (l & 3) ^ ((l >> 3) & 3);
  // u = global step 0..63; tile t = u>>3, K-slice c = u&7.
  auto STAGE = [&](int u, int b) {
    const int t = u >> 3, c = u & 7;
#pragma unroll
    for (int j = 0; j < 2; ++j) {
      const int r_l = w * 32 + j * 16 + (l >> 2);
      glds16(zbf + (size_t)(gBase + t * 128 + r_l) * DIM + c * 32 + ga0 * 8,
             &As[b][w * 32 + j * 16][0]);
      glds16(wbf + (size_t)(colBase + r_l) * DIM + c * 32 + ga0 * 8,
             &Bs[b][w * 32 + j * 16][0]);
    }
  };

  f32x4 acc[4][4];
#pragma unroll
  for (int mi = 0; mi < 4; ++mi)
#pragma unroll
    for (int ni = 0; ni < 4; ++ni) acc[mi][ni] = (f32x4){0.f, 0.f, 0.f, 0.f};

  const int chA = (lq ^ ((lr >> 1) & 3)) * 8;  // row = 16-aligned + lr

  auto COMPUTE = [&](int b) {
    bf16x8 af[4], bfr[4];
#pragma unroll
    for (int mi = 0; mi < 4; ++mi) af[mi] = *(const bf16x8*)&As[b][wr + mi * 16 + lr][chA];
#pragma unroll
    for (int ni = 0; ni < 4; ++ni) bfr[ni] = *(const bf16x8*)&Bs[b][wc + ni * 16 + lr][chA];
#pragma unroll
    for (int mi = 0; mi < 4; ++mi)
#pragma unroll
      for (int ni = 0; ni < 4; ++ni)
        acc[mi][ni] =
            __builtin_amdgcn_mfma_f32_16x16x32_bf16(af[mi], bfr[ni], acc[mi][ni], 0, 0, 0);
  };

  STAGE(0, 0);
  STAGE(1, 1);  // 8 glds16/lane in flight
  for (int u = 0; u < 64; ++u) {
    // stage u landed; stage u+1 (4 loads/lane) stays in flight across barrier
    if (u < 63)
      asm volatile("s_waitcnt vmcnt(4)" ::: "memory");
    else
      asm volatile("s_waitcnt vmcnt(0)" ::: "memory");
    __builtin_amdgcn_sched_barrier(0);
    __builtin_amdgcn_s_barrier();  // all waves' stage u landed
    __builtin_amdgcn_sched_barrier(0);
    COMPUTE(u & 1);
    __builtin_amdgcn_sched_barrier(0);
    __builtin_amdgcn_s_barrier();  // all waves done reading buf u&1
    if (u < 62) STAGE(u + 2, u & 1);  // refill; lands behind the reads

    if ((u & 7) == 7) {
      // Per-tile epilogue: registers + global only (no LDS, no barrier);
      // overlaps the already-issued DMA for the next tile's first slices.
      // C/D layout (validated): col = lane&15, row = (lane>>4)*4 + reg.
      const int rowBase = gBase + (u >> 3) * 128;
#pragma unroll
      for (int mi = 0; mi < 4; ++mi) {
        const float4 cutv =
            *(const float4*)(ws + WS_CUT0 + rowBase + wr + mi * 16 + lq * 4);
        const float cuta[4] = {cutv.x, cutv.y, cutv.z, cutv.w};
#pragma unroll
        for (int r = 0; r < 4; ++r) {
          const int lrow = wr + mi * 16 + lq * 4 + r;
          const float cut = cuta[r];
#pragma unroll
          for (int ni = 0; ni < 4; ++ni) {
            if (acc[mi][ni][r] >= cut) {
              const int grow = rowBase + lrow;
              const int gcol = colBase + wc + ni * 16 + lr;
              const unsigned int pos = atomicAdd(&cntp[grow], 1u);
              if (pos < CAP) {
                uint2 e;
                e.x = __float_as_uint(acc[mi][ni][r]);
                e.y = (unsigned int)gcol;
                candp[(size_t)grow * CAP + pos] = e;
              }
            }
          }
        }
        acc[mi][0] = (f32x4){0.f, 0.f, 0.f, 0.f};
        acc[mi][1] = (f32x4){0.f, 0.f, 0.f, 0.f};
        acc[mi][2] = (f32x4){0.f, 0.f, 0.f, 0.f};
        acc[mi][3] = (f32x4){0.f, 0.f, 0.f, 0.f};
      }
    }
  }
}

// One WAVE per row. Lanes 0..cv-1 load candidates coalesced; shuffle-reduce
// candmax; rigor gate unchanged. Survivors run the exact np dot_chain in
// parallel lanes; argmin via packed (dist_bits<<32 | k) key (dist ~ 256 > 0 ->
// uint order = float order; ties -> lowest k = np.argmin). Fallback rows get a
// -1 sentinel index; gather_loss resolves them from the u64 slots.
__global__ void recheck_kernel(const float* __restrict__ z, const float* __restrict__ W,
                               float* __restrict__ ws, const uint2* __restrict__ candp,
                               float* __restrict__ out) {
  const int lane = threadIdx.x & 63;
  const int row = blockIdx.x * 4 + (threadIdx.x >> 6);
  const unsigned int cv = ((const unsigned int*)ws)[WS_CNT + row];
  const float margin = ws[WS_MARGIN + row];
  const float cut0 = ws[WS_CUT0 + row];
  bool fb = (cv == 0u) || (cv > CAP);
  uint2 e;
  e.x = 0u; e.y = 0u;
  float av = -3.4e38f;
  if (!fb && lane < (int)cv) {
    e = candp[(size_t)row * CAP + lane];
    av = __uint_as_float(e.x);
  }
  float candmax = av;
#pragma unroll
  for (int s = 1; s < 64; s <<= 1) candmax = fmaxf(candmax, __shfl_xor(candmax, s, 64));
  if (!fb && candmax - margin < cut0) fb = true;  // cannot prove superset -> exact scan
  if (fb) {
    if (lane == 0) {
      ((unsigned long long*)((unsigned int*)ws + WS_SLOT))[row] = ~0ull;
      const unsigned int p = atomicAdd(&((unsigned int*)ws)[WS_OVF], 1u);
      ((unsigned int*)ws)[WS_OVFLIST + p] = (unsigned int)row;
      out[IDX_OFF + row] = -1.0f;  // sentinel: resolved by gather_loss
    }
    return;
  }
  const float fcut = candmax - margin;
  unsigned long long key = ~0ull;
  if (lane < (int)cv && av >= fcut) {  // below final cut: cannot be argmin
    const int k = (int)e.y;
    const float zn = ws[WS_ZNORM + row];
    const float m = dot_chain(z + (size_t)row * DIM, W + (size_t)k * DIM);
    const float dist = (zn + ws[WS_WNORM + k]) - 2.0f * m;
    key = ((unsigned long long)__float_as_uint(dist) << 32) | (unsigned int)k;
  }
#pragma unroll
  for (int s = 1; s < 64; s <<= 1) {
    const unsigned long long o = (unsigned long long)__shfl_xor((long long)key, s, 64);
    key = (o < key) ? o : key;
  }
  if (lane == 0) out[IDX_OFF + row] = (float)(unsigned int)(key & 0xffffffffull);
}

// Grid-parallel exact fallback: work item = (queued row, 256-code chunk). Each
// thread one code -> exact np dist; block-reduce min; u64 atomicMin combine.
__global__ void fallback_compute(const float* __restrict__ z, const float* __restrict__ W,
                                 float* __restrict__ ws) {
  __shared__ unsigned long long part[4];
  const unsigned int n = ((const unsigned int*)ws)[WS_OVF];
  unsigned long long* slots = (unsigned long long*)((unsigned int*)ws + WS_SLOT);
  const unsigned int total = n * 32u;
  for (unsigned int item = blockIdx.x; item < total; item += gridDim.x) {
    const int row = (int)((const unsigned int*)ws)[WS_OVFLIST + (item >> 5)];
    const int k = (int)(item & 31u) * 256 + threadIdx.x;
    const float zn = ws[WS_ZNORM + row];
    const float m = dot_chain(z + (size_t)row * DIM, W + (size_t)k * DIM);
    const float dist = (zn + ws[WS_WNORM + k]) - 2.0f * m;
    unsigned long long key =
        ((unsigned long long)__float_as_uint(dist) << 32) | (unsigned int)k;
#pragma unroll
    for (int s = 1; s < 64; s <<= 1) {
      const unsigned long long o = __shfl_xor((long long)key, s, 64);
      key = (o < key) ? o : key;
    }
    if ((threadIdx.x & 63) == 0) part[threadIdx.x >> 6] = key;
    __syncthreads();
    if (threadIdx.x == 0) {
      unsigned long long b = part[0];
      b = (part[1] < b) ? part[1] : b;
      b = (part[2] < b) ? part[2] : b;
      b = (part[3] < b) ? part[3] : b;
      atomicMin(&slots[row], b);
    }
    __syncthreads();
  }
}

// 64 rows/block: gather W[idx], quantized_st = z + (q - z), loss partial sums.
// Rows with the -1 sentinel read their exact-fallback result from the u64 slot.
__global__ void gather_loss_kernel(const float* __restrict__ z, const float* __restrict__ W,
                                   float* __restrict__ out, float* __restrict__ ws) {
  const int tid = threadIdx.x;
  const int rowBase = blockIdx.x * 64;
  float lsum = 0.0f;
  for (int p = 0; p < 16; ++p) {
    const int row = rowBase + p * 4 + (tid >> 6);
    const int c4 = tid & 63;
    int idx = (int)out[IDX_OFF + row];
    if (idx < 0) {
      const unsigned long long key =
          ((const unsigned long long*)((const unsigned int*)ws + WS_SLOT))[row];
      idx = (int)(unsigned int)(key & 0xffffffffull);
      out[IDX_OFF + row] = (float)idx;  // all 64 threads write same value: benign
    }
    const float4 zv = *(const float4*)(z + (size_t)row * DIM + c4 * 4);
    const float4 qv = *(const float4*)(W + (size_t)idx * DIM + c4 * 4);
    float4 t, o;
    t.x = qv.x - zv.x; t.y = qv.y - zv.y; t.z = qv.z - zv.z; t.w = qv.w - zv.w;
    o.x = zv.x + t.x;  o.y = zv.y + t.y;  o.z = zv.z + t.z;  o.w = zv.w + t.w;
    *(float4*)(out + (size_t)row * DIM + c4 * 4) = o;
    lsum += t.x * t.x + t.y * t.y + t.z * t.z + t.w * t.w;
  }
#pragma unroll
  for (int m = 1; m < 64; m <<= 1) lsum += __shfl_xor(lsum, m, 64);
  __shared__ float part[4];
  if ((tid & 63) == 0) part[tid >> 6] = lsum;
  __syncthreads();
  if (tid == 0) atomicAdd(&ws[WS_LOSS], (part[0] + part[1]) + (part[2] + part[3]));
}

__global__ void finalize_kernel(const float* __restrict__ ws, float* __restrict__ out) {
  if (threadIdx.x == 0 && blockIdx.x == 0) {
    const float mean = ws[WS_LOSS] / (float)(N_ROWS * DIM);
    out[LOSS_OFF] = mean + 0.25f * mean;
  }
}

extern "C" void kernel_launch(void* const* d_in, const int* in_sizes, int n_in,
                              void* d_out, int out_size, void* d_ws, size_t ws_size,
                              hipStream_t stream) {
  (void)in_sizes; (void)n_in; (void)out_size; (void)ws_size;
  const float* z = (const float*)d_in[0];
  const float* W = (const float*)d_in[1];
  float* out = (float*)d_out;
  float* ws = (float*)d_ws;
  unsigned short* outu = (unsigned short*)d_out;
  const unsigned short* wbf = outu + OUT_WBF_U16;
  const unsigned short* zbf = outu + OUT_ZBF_U16;
  uint2* candp = (uint2*)((float*)d_out + OUT_CAND_F);

  hipLaunchKernelGGL(prep_kernel, dim3((N_ROWS + K_CODES) / 16), dim3(256), 0, stream,
                     z, W, ws, outu);
  // 64 col-blocks x 64 row-groups; each block chains 8 row-tiles (64 K-steps).
  hipLaunchKernelGGL(gemm_screen_kernel, dim3(K_CODES / 128, N_ROWS / 1024), dim3(256),
                     0, stream, zbf, wbf, ws, candp);
  hipLaunchKernelGGL(recheck_kernel, dim3(N_ROWS / 4), dim3(256), 0, stream,
                     z, W, ws, candp, out);
  hipLaunchKernelGGL(fallback_compute, dim3(2048), dim3(256), 0, stream, z, W, ws);
  hipLaunchKernelGGL(gather_loss_kernel, dim3(N_ROWS / 64), dim3(256), 0, stream,
                     z, W, out, ws);
  hipLaunchKernelGGL(finalize_kernel, dim3(1), dim3(64), 0, stream, ws, out);
}

// Round 7
// 931.298 us; speedup vs baseline: 1.4525x; 1.4525x over previous
//
#include <hip/hip_runtime.h>

#define N_ROWS 65536
#define K_CODES 8192
#define DIM 256
#define CAP 56

// d_out layout (floats): [quantized_st 65536*256][loss 1][indices 65536]
#define LOSS_OFF (N_ROWS * DIM)
#define IDX_OFF (LOSS_OFF + 1)
// scratch inside d_out's quantized region (consumed before gather overwrites):
#define OUT_WBF_U16 0              // W fragments: 8192*256 u16  (4 MB)
#define OUT_ZBF_U16 2097152        // z fragments: 65536*256 u16 (32 MB)
#define OUT_CAND_F 9437184         // cand: 65536*56 uint2 (29.36 MB); ends exactly at 16777216

// d_ws layout (4-byte units), ~1.85 MB total
#define WS_LOSS 0
#define WS_ZNORM 64
#define WS_WNORM (WS_ZNORM + N_ROWS)
#define WS_MARGIN (WS_WNORM + K_CODES)
#define WS_CUT0 (WS_MARGIN + N_ROWS)
#define WS_CNT (WS_CUT0 + N_ROWS)       // uint
#define WS_OVF (WS_CNT + N_ROWS)        // uint counter
#define WS_OVFLIST (WS_OVF + 1)         // uint, up to N_ROWS
#define WS_SLOT (((WS_OVFLIST + N_ROWS) + 1) & ~1)  // u64 per row (8B aligned), 2*N_ROWS u32

typedef __bf16 bf16x8 __attribute__((ext_vector_type(8)));
typedef float f32x4 __attribute__((ext_vector_type(4)));

// ---------- numerics helpers ----------

__device__ __forceinline__ float mul_rn_nofma(float a, float b) {
  float r;
  asm("v_mul_f32 %0, %1, %2" : "=v"(r) : "v"(a), "v"(b));
  return r;
}

// fp32 -> bf16 bits, RNE (error <= 2^-8 rel; the margin derivation assumes this).
__device__ __forceinline__ unsigned int f2bf(float f) {
  unsigned int u = __float_as_uint(f);
  return (u + 0x7FFFu + ((u >> 16) & 1u)) >> 16;
}

// Exact np matmul replica: single ascending-d fmaf chain (bit-proven rounds 1-5).
__device__ float dot_chain(const float* __restrict__ zp, const float* __restrict__ wp) {
  float acc = 0.0f;
#pragma unroll 8
  for (int d4 = 0; d4 < 64; ++d4) {
    const float4 a = *(const float4*)(zp + d4 * 4);
    const float4 b = *(const float4*)(wp + d4 * 4);
    acc = fmaf(a.x, b.x, acc);
    acc = fmaf(a.y, b.y, acc);
    acc = fmaf(a.z, b.z, acc);
    acc = fmaf(a.w, b.w, acc);
  }
  return acc;
}

// ---------- kernels ----------

// FUSED precvt+norms. Norm reduction structure UNCHANGED (bit-exact numpy
// pairwise replica). NEW: bf16 copies are stored in MFMA-FRAGMENT ORDER so the
// GEMM can load operands directly global->VGPR, perfectly coalesced, no LDS.
// Element (r, d) -> u16 addr tile*32768 + ks*4096 + sub*512 + lq*128 + lr*8 + j
// where tile=r>>7, sub=((r>>6)&1)*4+((r>>4)&3), lr=r&15, ks=d>>5, lq=(d>>3)&3,
// j=d&7.  (Lane l=lq*16+lr of the MFMA fragment holds these 8 u16 as 16 B.)
// Store coalescing per instruction: lanes (rw,j) cover 64 contiguous bytes.
__global__ void prep_kernel(const float* __restrict__ z, const float* __restrict__ W,
                            float* __restrict__ ws, unsigned short* __restrict__ outu) {
  const int tid = threadIdx.x;
  const int l = tid & 63, w = tid >> 6;
  const int j = l & 7, b = (l >> 3) & 1, rw = l >> 4;
  const int row = blockIdx.x * 16 + w * 4 + rw;  // 0 .. 73727
  const bool isz = (row < N_ROWS);
  const int rr = isz ? row : (row - N_ROWS);
  const float* src = (isz ? z : W) + (size_t)rr * DIM + b * 128;
  unsigned short* fbp = outu + (isz ? OUT_ZBF_U16 : OUT_WBF_U16);
  const int tile = rr >> 7;
  const int sub = ((rr >> 6) & 1) * 4 + ((rr >> 4) & 3);
  const unsigned int basea =
      (unsigned int)tile * 32768u + (unsigned int)sub * 512u + (unsigned int)(rr & 15) * 8u + j;

  float a0 = src[j];
  {
    const int ksq = b * 16;  // t = 0
    fbp[basea + (ksq >> 2) * 4096 + (ksq & 3) * 128] = (unsigned short)f2bf(a0);
  }
  float r = mul_rn_nofma(a0, a0);
  float s = fabsf(a0);
  for (int i = 8; i < 128; i += 8) {
    const float v = src[i + j];
    const int ksq = b * 16 + (i >> 3);
    fbp[basea + (ksq >> 2) * 4096 + (ksq & 3) * 128] = (unsigned short)f2bf(v);
    r = r + mul_rn_nofma(v, v);
    s = s + fabsf(v);
  }
  // exact numpy pairwise tree: ((r0+r1)+(r2+r3))+((r4+r5)+(r6+r7)), then blk0+blk1
  r = r + __shfl_xor(r, 1, 64);
  r = r + __shfl_xor(r, 2, 64);
  r = r + __shfl_xor(r, 4, 64);
  r = r + __shfl_xor(r, 8, 64);
  s = s + __shfl_xor(s, 1, 64);
  s = s + __shfl_xor(s, 2, 64);
  s = s + __shfl_xor(s, 4, 64);
  s = s + __shfl_xor(s, 8, 64);
  if ((l & 15) == 0) {
    if (isz) {
      ws[WS_ZNORM + row] = r;
      const float margin = 2.0e-6f * s + 4.0e-5f;
      ws[WS_MARGIN + row] = margin;
      ws[WS_CUT0 + row] = 3.10f * sqrtf(r) * 7.0467e-5f - margin;
      ((unsigned int*)ws)[WS_CNT + row] = 0u;
    } else {
      ws[WS_WNORM + (row - N_ROWS)] = r;
    }
  }
  if (blockIdx.x == 0 && tid == 0) {
    ws[WS_LOSS] = 0.0f;
    ((unsigned int*)ws)[WS_OVF] = 0u;
  }
}

// bf16 MFMA screen GEMM - NO LDS, NO BARRIERS. Theory (r6 post-mortem): the
// LDS+barrier family is concurrency-capped (~2.4 blocks/CU) and 88% stalled;
// r0=r1=r4=563us across three sync schemes. With operands pre-stored in
// fragment order, each A/B fragment is ONE coalesced dwordx4 per wave,
// global->VGPR (L2-hot: 64 col-blocks share each z stripe under the proven
// x-major grid; W fragments are 4 MB). 4 independent waves/block free-run;
// fully-unrolled static 8-step K loop (r6 lesson); __launch_bounds__(256,3)
// caps VGPR at 168 (no spill expected: 64 acc + 32 frags + addr).
// Operand VALUES and per-acc MFMA order (ascending 32-wide K-slices) are
// bit-identical to r0/r4/r5 -> acc bits identical -> candidate set & margin
// proof intact.
__global__ __launch_bounds__(256, 3) void gemm_screen_kernel(
    const unsigned short* __restrict__ zfrag, const unsigned short* __restrict__ wfrag,
    float* __restrict__ ws, uint2* __restrict__ candp) {
  const int tid = threadIdx.x;
  const int w = tid >> 6, l = tid & 63;
  const int lr = l & 15, lq = l >> 4;
  const int wr = (w >> 1) * 64, wc = (w & 1) * 64;
  const int rowBase = blockIdx.y * 128, colBase = blockIdx.x * 128;
  unsigned int* cntp = (unsigned int*)ws + WS_CNT;

  // fragment pointers, 16B units: flat = tile*4096 + ks*512 + sub*64 + l
  const bf16x8* za =
      (const bf16x8*)zfrag + ((size_t)blockIdx.y * 64 + (w >> 1) * 4) * 64 + l;
  const bf16x8* wa =
      (const bf16x8*)wfrag + ((size_t)blockIdx.x * 64 + (w & 1) * 4) * 64 + l;

  f32x4 acc[4][4];
#pragma unroll
  for (int mi = 0; mi < 4; ++mi)
#pragma unroll
    for (int ni = 0; ni < 4; ++ni) acc[mi][ni] = (f32x4){0.f, 0.f, 0.f, 0.f};

#pragma unroll
  for (int ks = 0; ks < 8; ++ks) {
    bf16x8 af[4], bfr[4];
#pragma unroll
    for (int mi = 0; mi < 4; ++mi) af[mi] = za[(ks * 8 + mi) * 64];
#pragma unroll
    for (int ni = 0; ni < 4; ++ni) bfr[ni] = wa[(ks * 8 + ni) * 64];
#pragma unroll
    for (int mi = 0; mi < 4; ++mi)
#pragma unroll
      for (int ni = 0; ni < 4; ++ni)
        acc[mi][ni] =
            __builtin_amdgcn_mfma_f32_16x16x32_bf16(af[mi], bfr[ni], acc[mi][ni], 0, 0, 0);
  }

  // Append-only epilogue (r5-proven): C/D layout col = lane&15,
  // row = (lane>>4)*4 + reg; cuts read as float4 straight from ws.
#pragma unroll
  for (int mi = 0; mi < 4; ++mi) {
    const float4 cutv = *(const float4*)(ws + WS_CUT0 + rowBase + wr + mi * 16 + lq * 4);
    const float cuta[4] = {cutv.x, cutv.y, cutv.z, cutv.w};
#pragma unroll
    for (int r = 0; r < 4; ++r) {
      const int lrow = wr + mi * 16 + lq * 4 + r;
      const float cut = cuta[r];
#pragma unroll
      for (int ni = 0; ni < 4; ++ni) {
        if (acc[mi][ni][r] >= cut) {
          const int grow = rowBase + lrow;
          const int gcol = colBase + wc + ni * 16 + lr;
          const unsigned int pos = atomicAdd(&cntp[grow], 1u);
          if (pos < CAP) {
            uint2 e;
            e.x = __float_as_uint(acc[mi][ni][r]);
            e.y = (unsigned int)gcol;
            candp[(size_t)grow * CAP + pos] = e;
          }
        }
      }
    }
  }
}

// One WAVE per row. Lanes 0..cv-1 load candidates coalesced; shuffle-reduce
// candmax; rigor gate unchanged. Survivors run the exact np dot_chain in
// parallel lanes; argmin via packed (dist_bits<<32 | k) key (dist ~ 256 > 0 ->
// uint order = float order; ties -> lowest k = np.argmin). Fallback rows get a
// -1 sentinel index; gather_loss resolves them from the u64 slots.
__global__ void recheck_kernel(const float* __restrict__ z, const float* __restrict__ W,
                               float* __restrict__ ws, const uint2* __restrict__ candp,
                               float* __restrict__ out) {
  const int lane = threadIdx.x & 63;
  const int row = blockIdx.x * 4 + (threadIdx.x >> 6);
  const unsigned int cv = ((const unsigned int*)ws)[WS_CNT + row];
  const float margin = ws[WS_MARGIN + row];
  const float cut0 = ws[WS_CUT0 + row];
  bool fb = (cv == 0u) || (cv > CAP);
  uint2 e;
  e.x = 0u; e.y = 0u;
  float av = -3.4e38f;
  if (!fb && lane < (int)cv) {
    e = candp[(size_t)row * CAP + lane];
    av = __uint_as_float(e.x);
  }
  float candmax = av;
#pragma unroll
  for (int s = 1; s < 64; s <<= 1) candmax = fmaxf(candmax, __shfl_xor(candmax, s, 64));
  if (!fb && candmax - margin < cut0) fb = true;  // cannot prove superset -> exact scan
  if (fb) {
    if (lane == 0) {
      ((unsigned long long*)((unsigned int*)ws + WS_SLOT))[row] = ~0ull;
      const unsigned int p = atomicAdd(&((unsigned int*)ws)[WS_OVF], 1u);
      ((unsigned int*)ws)[WS_OVFLIST + p] = (unsigned int)row;
      out[IDX_OFF + row] = -1.0f;  // sentinel: resolved by gather_loss
    }
    return;
  }
  const float fcut = candmax - margin;
  unsigned long long key = ~0ull;
  if (lane < (int)cv && av >= fcut) {  // below final cut: cannot be argmin
    const int k = (int)e.y;
    const float zn = ws[WS_ZNORM + row];
    const float m = dot_chain(z + (size_t)row * DIM, W + (size_t)k * DIM);
    const float dist = (zn + ws[WS_WNORM + k]) - 2.0f * m;
    key = ((unsigned long long)__float_as_uint(dist) << 32) | (unsigned int)k;
  }
#pragma unroll
  for (int s = 1; s < 64; s <<= 1) {
    const unsigned long long o = (unsigned long long)__shfl_xor((long long)key, s, 64);
    key = (o < key) ? o : key;
  }
  if (lane == 0) out[IDX_OFF + row] = (float)(unsigned int)(key & 0xffffffffull);
}

// Grid-parallel exact fallback: work item = (queued row, 256-code chunk). Each
// thread one code -> exact np dist; block-reduce min; u64 atomicMin combine.
__global__ void fallback_compute(const float* __restrict__ z, const float* __restrict__ W,
                                 float* __restrict__ ws) {
  __shared__ unsigned long long part[4];
  const unsigned int n = ((const unsigned int*)ws)[WS_OVF];
  unsigned long long* slots = (unsigned long long*)((unsigned int*)ws + WS_SLOT);
  const unsigned int total = n * 32u;
  for (unsigned int item = blockIdx.x; item < total; item += gridDim.x) {
    const int row = (int)((const unsigned int*)ws)[WS_OVFLIST + (item >> 5)];
    const int k = (int)(item & 31u) * 256 + threadIdx.x;
    const float zn = ws[WS_ZNORM + row];
    const float m = dot_chain(z + (size_t)row * DIM, W + (size_t)k * DIM);
    const float dist = (zn + ws[WS_WNORM + k]) - 2.0f * m;
    unsigned long long key =
        ((unsigned long long)__float_as_uint(dist) << 32) | (unsigned int)k;
#pragma unroll
    for (int s = 1; s < 64; s <<= 1) {
      const unsigned long long o = __shfl_xor((long long)key, s, 64);
      key = (o < key) ? o : key;
    }
    if ((threadIdx.x & 63) == 0) part[threadIdx.x >> 6] = key;
    __syncthreads();
    if (threadIdx.x == 0) {
      unsigned long long b = part[0];
      b = (part[1] < b) ? part[1] : b;
      b = (part[2] < b) ? part[2] : b;
      b = (part[3] < b) ? part[3] : b;
      atomicMin(&slots[row], b);
    }
    __syncthreads();
  }
}

// 64 rows/block: gather W[idx], quantized_st = z + (q - z), loss partial sums.
// Rows with the -1 sentinel read their exact-fallback result from the u64 slot.
__global__ void gather_loss_kernel(const float* __restrict__ z, const float* __restrict__ W,
                                   float* __restrict__ out, float* __restrict__ ws) {
  const int tid = threadIdx.x;
  const int rowBase = blockIdx.x * 64;
  float lsum = 0.0f;
  for (int p = 0; p < 16; ++p) {
    const int row = rowBase + p * 4 + (tid >> 6);
    const int c4 = tid & 63;
    int idx = (int)out[IDX_OFF + row];
    if (idx < 0) {
      const unsigned long long key =
          ((const unsigned long long*)((const unsigned int*)ws + WS_SLOT))[row];
      idx = (int)(unsigned int)(key & 0xffffffffull);
      out[IDX_OFF + row] = (float)idx;  // all 64 threads write same value: benign
    }
    const float4 zv = *(const float4*)(z + (size_t)row * DIM + c4 * 4);
    const float4 qv = *(const float4*)(W + (size_t)idx * DIM + c4 * 4);
    float4 t, o;
    t.x = qv.x - zv.x; t.y = qv.y - zv.y; t.z = qv.z - zv.z; t.w = qv.w - zv.w;
    o.x = zv.x + t.x;  o.y = zv.y + t.y;  o.z = zv.z + t.z;  o.w = zv.w + t.w;
    *(float4*)(out + (size_t)row * DIM + c4 * 4) = o;
    lsum += t.x * t.x + t.y * t.y + t.z * t.z + t.w * t.w;
  }
#pragma unroll
  for (int m = 1; m < 64; m <<= 1) lsum += __shfl_xor(lsum, m, 64);
  __shared__ float part[4];
  if ((tid & 63) == 0) part[tid >> 6] = lsum;
  __syncthreads();
  if (tid == 0) atomicAdd(&ws[WS_LOSS], (part[0] + part[1]) + (part[2] + part[3]));
}

__global__ void finalize_kernel(const float* __restrict__ ws, float* __restrict__ out) {
  if (threadIdx.x == 0 && blockIdx.x == 0) {
    const float mean = ws[WS_LOSS] / (float)(N_ROWS * DIM);
    out[LOSS_OFF] = mean + 0.25f * mean;
  }
}

extern "C" void kernel_launch(void* const* d_in, const int* in_sizes, int n_in,
                              void* d_out, int out_size, void* d_ws, size_t ws_size,
                              hipStream_t stream) {
  (void)in_sizes; (void)n_in; (void)out_size; (void)ws_size;
  const float* z = (const float*)d_in[0];
  const float* W = (const float*)d_in[1];
  float* out = (float*)d_out;
  float* ws = (float*)d_ws;
  unsigned short* outu = (unsigned short*)d_out;
  const unsigned short* wfrag = outu + OUT_WBF_U16;
  const unsigned short* zfrag = outu + OUT_ZBF_U16;
  uint2* candp = (uint2*)((float*)d_out + OUT_CAND_F);

  hipLaunchKernelGGL(prep_kernel, dim3((N_ROWS + K_CODES) / 16), dim3(256), 0, stream,
                     z, W, ws, outu);
  hipLaunchKernelGGL(gemm_screen_kernel, dim3(K_CODES / 128, N_ROWS / 128), dim3(256),
                     0, stream, zfrag, wfrag, ws, candp);
  hipLaunchKernelGGL(recheck_kernel, dim3(N_ROWS / 4), dim3(256), 0, stream,
                     z, W, ws, candp, out);
  hipLaunchKernelGGL(fallback_compute, dim3(2048), dim3(256), 0, stream, z, W, ws);
  hipLaunchKernelGGL(gather_loss_kernel, dim3(N_ROWS / 64), dim3(256), 0, stream,
                     z, W, out, ws);
  hipLaunchKernelGGL(finalize_kernel, dim3(1), dim3(64), 0, stream, ws, out);
}